// Round 8
// baseline (366.897 us; speedup 1.0000x reference)
//
#include <hip/hip_runtime.h>

// 192^3 FDTD, two-pass STREAMING float4 (round 8 = round 7 resubmitted:
// previous bench was an infra failure, kernel never ran).
// R6 evidence: NT-load cache policy -10% -> memory-system-bound on re-read
// locality. This round localizes the 5x stencil re-reads per row:
//   - each XCD (hw bid%8) owns a contiguous 24-plane x-slab (864 blocks),
//     processed plane-major -> x+-1 / y+-1 re-reads hit that XCD's own L2
//     instead of duplicating lines across 8 XCD L2s;
//   - step2 uses the SAME slab->XCD mapping (reads H2/E from the L2 that
//     produced them), reversed within-slab (L3/L2 recency is LIFO);
//   - NT loads on single-use streams, NT stores on E2 (kept from R6).
// Math identical to the verified kernels: central differences only on the
// strict interior of all three dims; clamped addresses + per-element mask.

#define NXD 192
#define NYD 192
#define NZD 192

static constexpr int   N3     = NXD * NYD * NZD;   // 7,077,888
static constexpr int   NCHUNK = N3 / 4;            // 1,769,472
static constexpr float DTc    = 1e-12f;
static constexpr float INV2D  = 500.0f;            // 1/(2*1e-3)

static constexpr int KC = NZD / 4;                 // 48 chunks per z-row
static constexpr int NBLK = NCHUNK / 256;          // 6912 blocks
static constexpr int NXCD = 8;
static constexpr int BPX  = NBLK / NXCD;           // 864 blocks per XCD slab

typedef float vf4 __attribute__((ext_vector_type(4)));  // native vec for builtins

__device__ __forceinline__ int clampi(int v, int lo, int hi) {
    return v < lo ? lo : (v > hi ? hi : v);
}

__global__ __launch_bounds__(256) void fdtd_step1(
    const float* __restrict__ Ex, const float* __restrict__ Ey, const float* __restrict__ Ez,
    const float* __restrict__ Hx, const float* __restrict__ Hy, const float* __restrict__ Hz,
    const float* __restrict__ mu,
    float* __restrict__ Hx2, float* __restrict__ Hy2, float* __restrict__ Hz2)
{
    // XCD slab swizzle: hw assigns bid%8 -> XCD k; give XCD k the contiguous
    // slab of planes [24k, 24k+24), processed in increasing order.
    int bid  = (int)blockIdx.x;
    int swz  = (bid & 7) * BPX + (bid >> 3);
    int idx4 = swz * 256 + (int)threadIdx.x;

    int kc = idx4 % KC;
    int t  = idx4 / KC;
    int j  = t % NYD;
    int i  = t / NYD;
    int k0 = kc * 4;

    int ip = clampi(i + 1, 0, NXD - 1);
    int im = clampi(i - 1, 0, NXD - 1);
    int jp = clampi(j + 1, 0, NYD - 1);
    int jm = clampi(j - 1, 0, NYD - 1);
    int km1 = (k0 > 0) ? k0 - 1 : 0;               // only consumed when masked-valid
    int kp4 = (k0 < NZD - 4) ? k0 + 4 : NZD - 1;

    int rowC  = (i  * NYD + j ) * NZD;
    int rowXp = (ip * NYD + j ) * NZD;
    int rowXm = (im * NYD + j ) * NZD;
    int rowYp = (i  * NYD + jp) * NZD;
    int rowYm = (i  * NYD + jm) * NZD;

    // E loads: stencil-reused within step1 AND re-read by step2 -> keep cached.
    vf4 ezYp = *(const vf4*)(Ez + rowYp + k0);
    vf4 ezYm = *(const vf4*)(Ez + rowYm + k0);
    vf4 exYp = *(const vf4*)(Ex + rowYp + k0);
    vf4 exYm = *(const vf4*)(Ex + rowYm + k0);
    vf4 eyXp = *(const vf4*)(Ey + rowXp + k0);
    vf4 eyXm = *(const vf4*)(Ey + rowXm + k0);
    vf4 ezXp = *(const vf4*)(Ez + rowXp + k0);
    vf4 ezXm = *(const vf4*)(Ez + rowXm + k0);
    vf4 eyC  = *(const vf4*)(Ey + rowC + k0);
    vf4 exC  = *(const vf4*)(Ex + rowC + k0);
    float ey_m1 = Ey[rowC + km1], ey_p4 = Ey[rowC + kp4];
    float ex_m1 = Ex[rowC + km1], ex_p4 = Ex[rowC + kp4];
    // H, mu: single-use streams -> nontemporal (don't pollute L2/L3).
    vf4 hxC = __builtin_nontemporal_load((const vf4*)(Hx + rowC + k0));
    vf4 hyC = __builtin_nontemporal_load((const vf4*)(Hy + rowC + k0));
    vf4 hzC = __builtin_nontemporal_load((const vf4*)(Hz + rowC + k0));
    vf4 muC = __builtin_nontemporal_load((const vf4*)(mu + rowC + k0));

    vf4 vx, vy, vz;

    bool xyok = (i >= 1) && (i <= NXD - 2) && (j >= 1) && (j <= NYD - 2);
    #pragma unroll
    for (int e = 0; e < 4; ++e) {
        int ke = k0 + e;
        bool valid = xyok && (ke >= 1) && (ke <= NZD - 2);
        float eyzm = (e == 0) ? ey_m1 : eyC[e - 1];
        float eyzp = (e == 3) ? ey_p4 : eyC[e + 1];
        float exzm = (e == 0) ? ex_m1 : exC[e - 1];
        float exzp = (e == 3) ? ex_p4 : exC[e + 1];
        float cx = valid ? ((ezYp[e] - ezYm[e]) - (eyzp - eyzm)) * INV2D : 0.0f;
        float cy = valid ? ((exzp - exzm) - (ezXp[e] - ezXm[e])) * INV2D : 0.0f;
        float cz = valid ? ((eyXp[e] - eyXm[e]) - (exYp[e] - exYm[e])) * INV2D : 0.0f;
        float f = DTc / muC[e];
        vx[e] = hxC[e] - f * cx;
        vy[e] = hyC[e] - f * cy;
        vz[e] = hzC[e] - f * cz;
    }

    // H2 is re-read by step2: keep cached (normal stores).
    *(vf4*)(Hx2 + rowC + k0) = vx;
    *(vf4*)(Hy2 + rowC + k0) = vy;
    *(vf4*)(Hz2 + rowC + k0) = vz;
}

__global__ __launch_bounds__(256) void fdtd_step2(
    const float* __restrict__ Ex, const float* __restrict__ Ey, const float* __restrict__ Ez,
    const float* __restrict__ Hx2, const float* __restrict__ Hy2, const float* __restrict__ Hz2,
    const float* __restrict__ eps, const float* __restrict__ sigma,
    float* __restrict__ Ex2, float* __restrict__ Ey2, float* __restrict__ Ez2)
{
    // Same slab->XCD mapping as step1 (reuse the producing L2), but within
    // each slab consume blocks in REVERSE order (cache recency is LIFO).
    int bid  = (int)blockIdx.x;
    int swz  = (bid & 7) * BPX + (BPX - 1 - (bid >> 3));
    int idx4 = swz * 256 + (int)threadIdx.x;

    int kc = idx4 % KC;
    int t  = idx4 / KC;
    int j  = t % NYD;
    int i  = t / NYD;
    int k0 = kc * 4;

    int ip = clampi(i + 1, 0, NXD - 1);
    int im = clampi(i - 1, 0, NXD - 1);
    int jp = clampi(j + 1, 0, NYD - 1);
    int jm = clampi(j - 1, 0, NYD - 1);
    int km1 = (k0 > 0) ? k0 - 1 : 0;
    int kp4 = (k0 < NZD - 4) ? k0 + 4 : NZD - 1;

    int rowC  = (i  * NYD + j ) * NZD;
    int rowXp = (ip * NYD + j ) * NZD;
    int rowXm = (im * NYD + j ) * NZD;
    int rowYp = (i  * NYD + jp) * NZD;
    int rowYm = (i  * NYD + jm) * NZD;

    // H2: stencil-reused across threads/blocks -> NORMAL loads (keep L1/L2 hits).
    vf4 hzYp = *(const vf4*)(Hz2 + rowYp + k0);
    vf4 hzYm = *(const vf4*)(Hz2 + rowYm + k0);
    vf4 hxYp = *(const vf4*)(Hx2 + rowYp + k0);
    vf4 hxYm = *(const vf4*)(Hx2 + rowYm + k0);
    vf4 hyXp = *(const vf4*)(Hy2 + rowXp + k0);
    vf4 hyXm = *(const vf4*)(Hy2 + rowXm + k0);
    vf4 hzXp = *(const vf4*)(Hz2 + rowXp + k0);
    vf4 hzXm = *(const vf4*)(Hz2 + rowXm + k0);
    vf4 hyC  = *(const vf4*)(Hy2 + rowC + k0);
    vf4 hxC  = *(const vf4*)(Hx2 + rowC + k0);
    float hy_m1 = Hy2[rowC + km1], hy_p4 = Hy2[rowC + kp4];
    float hx_m1 = Hx2[rowC + km1], hx_p4 = Hx2[rowC + kp4];
    // E center, eps, sigma: last/single use -> nontemporal.
    vf4 exC  = __builtin_nontemporal_load((const vf4*)(Ex + rowC + k0));
    vf4 eyC  = __builtin_nontemporal_load((const vf4*)(Ey + rowC + k0));
    vf4 ezC  = __builtin_nontemporal_load((const vf4*)(Ez + rowC + k0));
    vf4 epsC = __builtin_nontemporal_load((const vf4*)(eps + rowC + k0));
    vf4 sigC = __builtin_nontemporal_load((const vf4*)(sigma + rowC + k0));

    vf4 ex2, ey2, ez2;

    bool xyok = (i >= 1) && (i <= NXD - 2) && (j >= 1) && (j <= NYD - 2);
    #pragma unroll
    for (int e = 0; e < 4; ++e) {
        int ke = k0 + e;
        bool valid = xyok && (ke >= 1) && (ke <= NZD - 2);
        float hyzm = (e == 0) ? hy_m1 : hyC[e - 1];
        float hyzp = (e == 3) ? hy_p4 : hyC[e + 1];
        float hxzm = (e == 0) ? hx_m1 : hxC[e - 1];
        float hxzp = (e == 3) ? hx_p4 : hxC[e + 1];
        float cx = valid ? ((hzYp[e] - hzYm[e]) - (hyzp - hyzm)) * INV2D : 0.0f;
        float cy = valid ? ((hxzp - hxzm) - (hzXp[e] - hzXm[e])) * INV2D : 0.0f;
        float cz = valid ? ((hyXp[e] - hyXm[e]) - (hxYp[e] - hxYm[e])) * INV2D : 0.0f;

        float ee = epsC[e];
        float ss = sigC[e];
        float half_sdt_over_e = ss * DTc / (2.0f * ee);
        float Ap = 1.0f + half_sdt_over_e;
        float Am = 1.0f - half_sdt_over_e;
        float coefE = Am / Ap;
        float coefC = DTc / (ee * Ap);
        ex2[e] = coefE * exC[e] + coefC * cx;
        ey2[e] = coefE * eyC[e] + coefC * cy;
        ez2[e] = coefE * ezC[e] + coefC * cz;
    }

    // E2 is never re-read: nontemporal stores.
    __builtin_nontemporal_store(ex2, (vf4*)(Ex2 + rowC + k0));
    __builtin_nontemporal_store(ey2, (vf4*)(Ey2 + rowC + k0));
    __builtin_nontemporal_store(ez2, (vf4*)(Ez2 + rowC + k0));
}

extern "C" void kernel_launch(void* const* d_in, const int* in_sizes, int n_in,
                              void* d_out, int out_size, void* d_ws, size_t ws_size,
                              hipStream_t stream)
{
    // setup_inputs order: Ex, Ey, Ez, Hx, Hy, Hz, eps, mu, sigma
    const float* Ex    = (const float*)d_in[0];
    const float* Ey    = (const float*)d_in[1];
    const float* Ez    = (const float*)d_in[2];
    const float* Hx    = (const float*)d_in[3];
    const float* Hy    = (const float*)d_in[4];
    const float* Hz    = (const float*)d_in[5];
    const float* eps   = (const float*)d_in[6];
    const float* mu    = (const float*)d_in[7];
    const float* sigma = (const float*)d_in[8];

    // outputs concatenated flat in return order: ex2, ey2, ez2, hx2, hy2, hz2
    float* out = (float*)d_out;
    float* Ex2 = out + 0 * (size_t)N3;
    float* Ey2 = out + 1 * (size_t)N3;
    float* Ez2 = out + 2 * (size_t)N3;
    float* Hx2 = out + 3 * (size_t)N3;
    float* Hy2 = out + 4 * (size_t)N3;
    float* Hz2 = out + 5 * (size_t)N3;

    const int block = 256;

    fdtd_step1<<<NBLK, block, 0, stream>>>(Ex, Ey, Ez, Hx, Hy, Hz, mu, Hx2, Hy2, Hz2);
    fdtd_step2<<<NBLK, block, 0, stream>>>(Ex, Ey, Ez, Hx2, Hy2, Hz2, eps, sigma, Ex2, Ey2, Ez2);
}